// Round 3
// baseline (227.729 us; speedup 1.0000x reference)
//
#include <hip/hip_runtime.h>
#include <hip/hip_bf16.h>
#include <stdint.h>

// Problem: B=4, N=1024, C=768, H=12, hd=64.
// out_x = (attn(qx,kx,vx,+) + attn(qyo,kx,vx,-)) @ Wp^T + bp
// out_y = (attn(qy,ky,vx,+) + attn(qxo,ky,vx,-)) @ Wp^T + bp   (vy = vx!)
// qkv[b,n, j*768 + h*64 + d], j in {0:qo, 1:q, 2:k, 3:v}
// NOTE: w_qkv rows j=0 are pre-scaled by -0.125*log2(e), j=1 by +0.125*log2(e)
// in cvt_bf16, so attention scores emerge in the log2 domain with sign folded:
// softmax is exp2(s) directly for BOTH self and cross attends.

#define BB 4
#define NN 1024
#define CC 768
#define HH 12
#define HD 64

typedef unsigned short u16;
typedef short short8 __attribute__((ext_vector_type(8)));
typedef float f32x4 __attribute__((ext_vector_type(4)));
typedef float f32x16 __attribute__((ext_vector_type(16)));

extern "C" __device__ float __ocml_native_exp2_f32(float);

__device__ __forceinline__ u16 f2bf(float f) {
  unsigned int u = __float_as_uint(f);
  return (u16)((u + 0x7fffu + ((u >> 16) & 1u)) >> 16);
}

__device__ __forceinline__ void load_lds16(const u16* g, u16* l) {
  __builtin_amdgcn_global_load_lds((__attribute__((address_space(1))) const void*)g,
                                   (__attribute__((address_space(3))) void*)l, 16, 0, 0);
}

// v_permlane32_swap_b32: a' = {a[0:32], b[0:32]}, b' = {a[32:64], b[32:64]}
__device__ __forceinline__ void pl32swap(unsigned& a, unsigned& b) {
  asm("v_permlane32_swap_b32 %0, %1" : "+v"(a), "+v"(b));
}

// pack two f32 -> u32 of 2 bf16 (truncated): low16 = hi16(e0), high16 = hi16(e1)
__device__ __forceinline__ unsigned pack_hi(float e0, float e1) {
  return __builtin_amdgcn_perm(__float_as_uint(e1), __float_as_uint(e0), 0x07060302u);
}

// fp32 -> bf16 conversion: seg 0=x, 1=y, 2=w_qkv (query rows pre-scaled), 3=w_proj
__global__ __launch_bounds__(256)
void cvt_bf16(const float* __restrict__ x, const float* __restrict__ y,
              const float* __restrict__ wq, const float* __restrict__ wp,
              u16* __restrict__ xb, u16* __restrict__ yb,
              u16* __restrict__ wqb, u16* __restrict__ wpb)
{
  const int seg = blockIdx.y;
  const float* src = seg == 0 ? x : (seg == 1 ? y : (seg == 2 ? wq : wp));
  u16* dst = seg == 0 ? xb : (seg == 1 ? yb : (seg == 2 ? wqb : wpb));
  const int n = (seg == 3) ? 768 * 768 : ((seg == 2) ? 3072 * 768 : 4096 * 768);
  const int i = (blockIdx.x * 256 + threadIdx.x) * 8;
  if (i >= n) return;
  float sc = 1.0f;
  if (seg == 2) {
    const int row = i / 768;  // output feature p; j = p/768
    sc = (row < 768) ? -0.18033688f : (row < 1536 ? 0.18033688f : 1.0f);
  }
  float4 a = *(const float4*)(src + i);
  float4 b = *(const float4*)(src + i + 4);
  ushort4 u0 = {f2bf(a.x * sc), f2bf(a.y * sc), f2bf(a.z * sc), f2bf(a.w * sc)};
  ushort4 u1 = {f2bf(b.x * sc), f2bf(b.y * sc), f2bf(b.z * sc), f2bf(b.w * sc)};
  *(ushort4*)(dst + i) = u0;
  *(ushort4*)(dst + i + 4) = u1;
}

// V^T prepass: VT[(bh*64 + d)*1024 + key] = qkv_x[b, key, 3*768 + h*64 + d]
__global__ __launch_bounds__(256)
void vtrans(const u16* __restrict__ qkvx, u16* __restrict__ VT)
{
  const int blk = blockIdx.x;                 // 1536 blocks
  const int xcd = blk & 7, slot = blk >> 3;   // 192 slots
  const int bh = (slot >> 5) * 8 + xcd;       // 6 groups x 8 = 48
  const int kt = slot & 31;                   // 32 key-tiles
  const int b = bh / HH, h = bh % HH;
  const int t = threadIdx.x;
  const int key = kt * 32 + (t >> 3), d0 = (t & 7) * 8;
  uint4 v = *(const uint4*)(qkvx + (size_t)(b * NN + key) * 3072 + 3 * CC + h * HD + d0);
  u16 e[8];
  *(uint4*)e = v;
#pragma unroll
  for (int i = 0; i < 8; i++)
    VT[(size_t)(bh * 64 + d0 + i) * 1024 + key] = e[i];
}

// MFMA GEMM: C[m,p] = A[m,:] . W[p,:] (+bias). 128x128 tile, 4 waves, BK=64.
// NZ1: column limit for blockIdx.z==1 (qkv_y's v-block j=3 is never read:
// vy := vx -> skip n0 >= 2304 for the y input, 12.5% of the QKV GEMM).
template<int NP, bool BF16OUT, bool BIAS, int NZ1>
__global__ __launch_bounds__(256)
void gemm_mfma(const u16* __restrict__ A0, const u16* __restrict__ A1,
               const u16* __restrict__ W, const float* __restrict__ bias,
               void* __restrict__ C0, void* __restrict__ C1)
{
  __shared__ u16 As[128 * 64];
  __shared__ u16 Bs[128 * 64];
  const int m0 = blockIdx.y * 128, n0 = blockIdx.x * 128;
  if (blockIdx.z && n0 >= NZ1) return;
  const u16* A = blockIdx.z ? A1 : A0;
  void* C = blockIdx.z ? C1 : C0;
  const int t = threadIdx.x, w = t >> 6, lane = t & 63;
  const int c = lane & 15, qq = lane >> 4;
  const int mq = (w >> 1) * 64, nq = (w & 1) * 64;

  const int lrow = lane >> 3;
  const int lchunk = (lane & 7) ^ lrow;
  size_t arow[4], brow[4];
#pragma unroll
  for (int i = 0; i < 4; i++) {
    const int r = (w * 4 + i) * 8 + lrow;
    arow[i] = (size_t)(m0 + r) * 768 + lchunk * 8;
    brow[i] = (size_t)(n0 + r) * 768 + lchunk * 8;
  }

  f32x4 acc[4][4] = {};
  for (int k0 = 0; k0 < 768; k0 += 64) {
    __syncthreads();
#pragma unroll
    for (int i = 0; i < 4; i++) {
      load_lds16(A + arow[i] + k0, As + (w * 4 + i) * 512);
      load_lds16(W + brow[i] + k0, Bs + (w * 4 + i) * 512);
    }
    __syncthreads();
#pragma unroll
    for (int s = 0; s < 2; s++) {
      const int swz = ((s * 4 + qq) ^ (c & 7)) * 8;
      short8 af[4], bf[4];
#pragma unroll
      for (int i = 0; i < 4; i++)
        af[i] = *(const short8*)&As[(mq + i * 16 + c) * 64 + swz];
#pragma unroll
      for (int j = 0; j < 4; j++)
        bf[j] = *(const short8*)&Bs[(nq + j * 16 + c) * 64 + swz];
#pragma unroll
      for (int i = 0; i < 4; i++)
#pragma unroll
        for (int j = 0; j < 4; j++)
          acc[i][j] = __builtin_amdgcn_mfma_f32_16x16x32_bf16(af[i], bf[j], acc[i][j], 0, 0, 0);
    }
  }
  float bj[4] = {0.f, 0.f, 0.f, 0.f};
  if (BIAS) {
#pragma unroll
    for (int j = 0; j < 4; j++) bj[j] = bias[n0 + nq + c + j * 16];
  }
#pragma unroll
  for (int i = 0; i < 4; i++)
#pragma unroll
    for (int r = 0; r < 4; r++) {
      const size_t row = (size_t)(m0 + mq + i * 16 + qq * 4 + r) * NP + n0 + nq + c;
      if (BF16OUT) {
#pragma unroll
        for (int j = 0; j < 4; j++)
          ((u16*)C)[row + j * 16] = f2bf(acc[i][j][r]);
      } else {
#pragma unroll
        for (int j = 0; j < 4; j++)
          ((float*)C)[row + j * 16] = acc[i][j][r] + bj[j];
      }
    }
}

// MFMA attention v9 — 32x32x16 MFMA + in-register P (permlane32_swap), dbuf.
// v6/v8 were LDS-pipe-bound: 28.7 KB LDS traffic per wave-iter (20 b128 reads
// + P writes), ~43 of 70 us. v9 halves fragment traffic with the 32x32 shape
// (2x arithmetic intensity per fragment byte: waves split 2x2 over q-half x
// key-half; K-frags 4 b128, V-frags 4 b128 per iter) and eliminates P-LDS
// entirely: the S^T -> PV-A-frag redistribution is exactly 4
// v_permlane32_swap_b32 per set (32x32 C/D layout: col=lane&31,
// row=(reg&3)+8(reg>>2)+4(lane>>5); A-frag: row=lane&31, k=8(lane>>5)+0..7).
// P is bf16-TRUNCATED (as before); L is the f32 sum of the SAME truncated
// values (in-lane tree + 1 permlane swap) so normalization cancels exactly.
// LDS = 32 KB (K/VT double-buffer only); 1 barrier per K-tile.
__global__ __launch_bounds__(256, 2)
void attn_pair_mfma(const u16* __restrict__ qkvx, const u16* __restrict__ qkvy,
                    const u16* __restrict__ VT,
                    u16* __restrict__ sum_x, u16* __restrict__ sum_y)
{
  // u16 layout: K0 [0,4096) K1 [4096,8192) V0 [8192,12288) V1 [12288,16384)
  // epilogue alias: Of 64x68 f32 = u16 [0,8704); Lbuf f32[256] = u16 [8704,9216)
  __shared__ __align__(16) u16 smem[16384];
  float (*Of)[68] = (float(*)[68])smem;
  float* LfB = (float*)(smem + 8704);

  // XCD-aware decode (perf heuristic only)
  const int blk = blockIdx.x;                // 1536 blocks
  const int xcd = blk & 7, slot = blk >> 3;  // 192 slots
  const int bh = (slot >> 5) * 8 + xcd;      // 6 groups x 8 = 48
  const int inner = slot & 31;
  const int qt = inner >> 1, pair = inner & 1;
  const int b = bh / HH, head = bh % HH;
  const u16* q1 = pair ? qkvy : qkvx;  // self q   (j=1, +scale folded)
  const u16* q2 = pair ? qkvx : qkvy;  // cross qo (j=0, -scale folded)
  const u16* ks = pair ? qkvy : qkvx;  // k (j=2)
  u16* outp = pair ? sum_y : sum_x;

  const int t = threadIdx.x, w = t >> 6, lane = t & 63;
  const int qh = w >> 1, kh = w & 1;   // wave = (q-half, key-half)
  const int c31 = lane & 31, h = lane >> 5;

  // Q B-frags: lane holds Q[qrow = qt*64+32qh+c31][d = 16c+8h .. +7], 2 sets
  short8 Qf[2][4];
  {
    const int qrow = qt * 64 + qh * 32 + c31;
    const u16* qs = q1 + (size_t)(b * NN + qrow) * 3072 + CC + head * HD + 8 * h;
    const u16* qc = q2 + (size_t)(b * NN + qrow) * 3072 + head * HD + 8 * h;
#pragma unroll
    for (int cc = 0; cc < 4; cc++) {
      Qf[0][cc] = *(const short8*)(qs + 16 * cc);
      Qf[1][cc] = *(const short8*)(qc + 16 * cc);
    }
  }

  const u16* kbase = ks + (size_t)(b * NN) * 3072 + 2 * CC + head * HD;
  const u16* vtb = VT + (size_t)(bh * 64) * 1024;

  const int lr = lane >> 3;
  const int sc8 = ((lane & 7) ^ lr) * 8;   // staging source swizzle (LDS[r][j]=G[r][j^(r&7)])
  const int x7 = c31 & 7;

  f32x16 O[2][2] = {};   // [set][d-col-block]
  float Lh[2] = {0.f, 0.f};

  // prologue: stage tile 0 into buffer 0
#pragma unroll
  for (int i = 0; i < 2; i++) {
    const int r = (2 * w + i) * 8 + lr;
    load_lds16(kbase + (size_t)r * 3072 + sc8, smem + (2 * w + i) * 512);
    load_lds16(vtb + (size_t)r * 1024 + sc8, smem + 8192 + (2 * w + i) * 512);
  }
  __syncthreads();

  for (int c16 = 0; c16 < 16; ++c16) {
    const int cur = c16 & 1;
    const u16* Kb = smem + cur * 4096;
    const u16* Vb = smem + 8192 + cur * 4096;

    // issue next-tile staging before compute (latency hides under MFMA/exp2)
    if (c16 < 15) {
      u16* Kn = smem + (cur ^ 1) * 4096;
      u16* Vn = smem + 8192 + (cur ^ 1) * 4096;
#pragma unroll
      for (int i = 0; i < 2; i++) {
        const int r = (2 * w + i) * 8 + lr;
        load_lds16(kbase + (size_t)((c16 + 1) * 64 + r) * 3072 + sc8,
                   Kn + (2 * w + i) * 512);
        load_lds16(vtb + (size_t)r * 1024 + (c16 + 1) * 64 + sc8,
                   Vn + (2 * w + i) * 512);
      }
    }

    // K A-frags: row = kh*32 + c31 (key), chunk (2c+h)^(row&7). Conflict-free:
    // each 8-lane phase group has distinct positions.
    short8 kf[4];
#pragma unroll
    for (int cc = 0; cc < 4; cc++)
      kf[cc] = *(const short8*)(Kb + (kh * 32 + c31) * 64 + (((2 * cc + h) ^ x7) * 8));
    // V B-frags: row = dc*32 + c31 (d), key-chunk (4kh + 2kc + h)^(row&7)
    short8 vf[2][2];
#pragma unroll
    for (int dc = 0; dc < 2; dc++)
#pragma unroll
      for (int kc = 0; kc < 2; kc++)
        vf[dc][kc] = *(const short8*)(Vb + (dc * 32 + c31) * 64 +
                                      (((4 * kh + 2 * kc + h) ^ x7) * 8));

#pragma unroll
    for (int s = 0; s < 2; s++) {
      // S^T = K . Q^T (32 keys x 32 q), k = d in 4 chunks of 16
      f32x16 z = {0.f, 0.f, 0.f, 0.f, 0.f, 0.f, 0.f, 0.f,
                  0.f, 0.f, 0.f, 0.f, 0.f, 0.f, 0.f, 0.f};
#pragma unroll
      for (int cc = 0; cc < 4; cc++)
        z = __builtin_amdgcn_mfma_f32_32x32x16_bf16(kf[cc], Qf[s][cc], z, 0, 0, 0);

      // exp2 + bf16-truncate; L accumulates the truncated values (consistent)
      float e[16];
#pragma unroll
      for (int r = 0; r < 16; r++) {
        float v = __ocml_native_exp2_f32(z[r]);
        e[r] = __uint_as_float(__float_as_uint(v) & 0xFFFF0000u);
      }
      Lh[s] += ((((e[0] + e[1]) + (e[2] + e[3])) + ((e[4] + e[5]) + (e[6] + e[7]))) +
                (((e[8] + e[9]) + (e[10] + e[11])) + ((e[12] + e[13]) + (e[14] + e[15]))));

      // pack into bf16 pairs: pk[g][t] = keys (8g+4h+2t, +1) for this lane's half h
      unsigned pk[4][2];
#pragma unroll
      for (int g = 0; g < 4; g++) {
        pk[g][0] = pack_hi(e[4 * g + 0], e[4 * g + 1]);
        pk[g][1] = pack_hi(e[4 * g + 2], e[4 * g + 3]);
      }
      // permlane32_swap builds PV A-frags: lane(h) chunk kc holds keys 16kc+8h+0..7
      unsigned a00 = pk[0][0], a20 = pk[1][0]; pl32swap(a00, a20);
      unsigned a10 = pk[0][1], a30 = pk[1][1]; pl32swap(a10, a30);
      unsigned a01 = pk[2][0], a21 = pk[3][0]; pl32swap(a01, a21);
      unsigned a11 = pk[2][1], a31 = pk[3][1]; pl32swap(a11, a31);
      union { unsigned u[4]; short8 s8; } pa0, pa1;
      pa0.u[0] = a00; pa0.u[1] = a10; pa0.u[2] = a20; pa0.u[3] = a30;
      pa1.u[0] = a01; pa1.u[1] = a11; pa1.u[2] = a21; pa1.u[3] = a31;

      // PV: O[q][d] += P[q][key] . V[key][d]
#pragma unroll
      for (int dc = 0; dc < 2; dc++) {
        O[s][dc] = __builtin_amdgcn_mfma_f32_32x32x16_bf16(pa0.s8, vf[dc][0], O[s][dc], 0, 0, 0);
        O[s][dc] = __builtin_amdgcn_mfma_f32_32x32x16_bf16(pa1.s8, vf[dc][1], O[s][dc], 0, 0, 0);
      }
    }

    __syncthreads();  // all reads of buf[cur] done; buf[cur^1] staged
  }

  // ---- epilogue ----
  // cross-half L: swap a copy across lane^32 and add -> full-wave L[q=c31]
  float Lw[2];
#pragma unroll
  for (int s = 0; s < 2; s++) {
    unsigned ua = __float_as_uint(Lh[s]), ub = __float_as_uint(Lh[s]);
    pl32swap(ua, ub);
    Lw[s] = __uint_as_float(ua) + __uint_as_float(ub);
  }
  if (lane < 32) {
    LfB[0 + kh * 64 + qh * 32 + lane] = Lw[0];    // set 0: [kh][q]
    LfB[128 + kh * 64 + qh * 32 + lane] = Lw[1];  // set 1
  }
  __syncthreads();

  // normalize per set with L_tot (kh0+kh1) and combine sets, in-register.
  // O reg r maps to q-row qh*32 + (r&3)+8*(r>>2)+4h (same pattern as L reads).
  float oc[2][16];
#pragma unroll
  for (int r = 0; r < 16; r++) {
    const int q = qh * 32 + (r & 3) + 8 * (r >> 2) + 4 * h;
    const float iL0 = 1.0f / (LfB[q] + LfB[64 + q]);
    const float iL1 = 1.0f / (LfB[128 + q] + LfB[192 + q]);
    oc[0][r] = O[0][0][r] * iL0 + O[1][0][r] * iL1;
    oc[1][r] = O[0][1][r] * iL0 + O[1][1][r] * iL1;
  }
  // cross-wave (key-half) reduction in LDS
  if (kh == 0) {
#pragma unroll
    for (int r = 0; r < 16; r++) {
      const int q = qh * 32 + (r & 3) + 8 * (r >> 2) + 4 * h;
      Of[q][c31] = oc[0][r];
      Of[q][32 + c31] = oc[1][r];
    }
  }
  __syncthreads();
  if (kh == 1) {
#pragma unroll
    for (int r = 0; r < 16; r++) {
      const int q = qh * 32 + (r & 3) + 8 * (r >> 2) + 4 * h;
      Of[q][c31] += oc[0][r];
      Of[q][32 + c31] += oc[1][r];
    }
  }
  __syncthreads();
  // out[b, qt*64+row, head*64+d] (bf16, coalesced)
#pragma unroll
  for (int p = 0; p < 4; p++) {
    const int idx = p * 256 + t;
    const int row = idx >> 4, c4 = (idx & 15) * 4;
    float4 v = *(const float4*)&Of[row][c4];
    ushort4 u = {f2bf(v.x), f2bf(v.y), f2bf(v.z), f2bf(v.w)};
    *(ushort4*)(outp + (size_t)(b * NN + qt * 64 + row) * CC + head * HD + c4) = u;
  }
}

extern "C" void kernel_launch(void* const* d_in, const int* in_sizes, int n_in,
                              void* d_out, int out_size, void* d_ws, size_t ws_size,
                              hipStream_t stream)
{
  const float* x      = (const float*)d_in[0];
  const float* y      = (const float*)d_in[1];
  const float* w_qkv  = (const float*)d_in[2];
  const float* w_proj = (const float*)d_in[3];
  const float* b_proj = (const float*)d_in[4];

  // ws layout (75.1 MB used):
  //   qkv_x 25.2 | qkv_y 25.2 | sum_x 6.3 (alias x_bf) | sum_y 6.3 (alias y_bf)
  //   | wq_bf 4.7 | wp_bf 1.2 | VT 6.3
  u16* qkv_x = (u16*)d_ws;
  u16* qkv_y = qkv_x + (size_t)4096 * 3072;
  u16* rest = qkv_y + (size_t)4096 * 3072;
  u16* sum_x = rest;
  u16* sum_y = sum_x + (size_t)4096 * 768;
  u16* x_bf  = rest;                       // aliases sum_x (dead after QKV)
  u16* y_bf  = x_bf + (size_t)4096 * 768;  // aliases sum_y
  u16* wq_bf = y_bf + (size_t)4096 * 768;
  u16* wp_bf = wq_bf + (size_t)3072 * 768;
  u16* VT    = wp_bf + (size_t)768 * 768;
  float* out_x = (float*)d_out;
  float* out_y = out_x + (size_t)4096 * 768;

  // 0) fp32 -> bf16 (w_qkv query rows pre-scaled by ±0.125·log2e)
  cvt_bf16<<<dim3(1536, 4), 256, 0, stream>>>(x, y, w_qkv, w_proj,
                                              x_bf, y_bf, wq_bf, wp_bf);

  // 1) QKV via MFMA: qkv_{x,y} = {x,y}_bf @ wq_bf^T (bf16 out).
  //    y skips its dead v-block (n0 >= 2304).
  gemm_mfma<3072, true, false, 2304><<<dim3(24, 32, 2), 256, 0, stream>>>(
      x_bf, y_bf, wq_bf, nullptr, qkv_x, qkv_y);

  // 1.5) V^T prepass (v always from x), XCD-swizzled
  vtrans<<<dim3(1536), 256, 0, stream>>>(qkv_x, VT);

  // 2) paired MFMA attention -> sum_x, sum_y (bf16), XCD-swizzled 1-D grid
  attn_pair_mfma<<<dim3(1536), 256, 0, stream>>>(qkv_x, qkv_y, VT, sum_x, sum_y);

  // 3) out = sum @ wp_bf^T + b_proj (f32, MFMA)
  gemm_mfma<768, false, true, 768><<<dim3(6, 32, 2), 256, 0, stream>>>(
      sum_x, sum_y, wp_bf, b_proj, out_x, out_y);
}